// Round 6
// baseline (409.306 us; speedup 1.0000x reference)
//
#include <hip/hip_runtime.h>
#include <hip/hip_bf16.h>
#include <math.h>

#define NN 50000
#define NE 600000
#define HD 128
#define NL 3
#define NBLK 49     // ceil(NN/1024)
#define GBLK 12500  // blocks per channel-group in aggregate4 (4 nodes/block)

typedef __attribute__((ext_vector_type(8))) short short8;
typedef __attribute__((ext_vector_type(4))) float f32x4;

__device__ __forceinline__ ushort f2bf(float v) {
    union { float f; unsigned u; } c; c.f = v;
    unsigned u = c.u;
    u = (u + 0x7fffu + ((u >> 16) & 1u)) >> 16;
    return (ushort)u;
}
__device__ __forceinline__ float u2f(uint u) {
    union { uint u; float f; } c; c.u = u; return c.f;
}

// ---------------- degree ----------------

__global__ void count_deg_k(const int* __restrict__ dst, int* __restrict__ deg) {
    int e = blockIdx.x * blockDim.x + threadIdx.x;
    if (e < NE) atomicAdd(&deg[dst[e]], 1);
}

// ---------------- 3-phase scan: deg -> rowptr (exclusive) ----------------

__global__ __launch_bounds__(1024) void scan_partial_k(const int* __restrict__ deg,
                                                       int* __restrict__ rowptr,
                                                       int* __restrict__ partial) {
    __shared__ int wsum[16];
    int tid = threadIdx.x;
    int lane = tid & 63, w = tid >> 6;
    int v = blockIdx.x * 1024 + tid;
    int x = (v < NN) ? deg[v] : 0;
    int s = x;
    #pragma unroll
    for (int off = 1; off < 64; off <<= 1) {
        int t = __shfl_up(s, off);
        if (lane >= off) s += t;
    }
    if (lane == 63) wsum[w] = s;
    __syncthreads();
    if (w == 0) {
        int t = (lane < 16) ? wsum[lane] : 0;
        #pragma unroll
        for (int off = 1; off < 16; off <<= 1) {
            int u = __shfl_up(t, off);
            if (lane >= off) t += u;
        }
        if (lane < 16) wsum[lane] = t;
    }
    __syncthreads();
    int incl = s + ((w > 0) ? wsum[w - 1] : 0);
    if (v < NN) rowptr[v] = incl - x;
    if (tid == 1023) partial[blockIdx.x] = incl;
}

__global__ void scan_partials2_k(int* __restrict__ partial) {
    int lane = threadIdx.x & 63;
    int x = (lane < NBLK) ? partial[lane] : 0;
    int s = x;
    #pragma unroll
    for (int off = 1; off < 64; off <<= 1) {
        int t = __shfl_up(s, off);
        if (lane >= off) s += t;
    }
    if (lane < NBLK) partial[lane] = s - x;
    if (lane == NBLK - 1) partial[NBLK] = s;
}

__global__ __launch_bounds__(1024) void add_off_isq_k(const int* __restrict__ deg,
                                                      int* __restrict__ rowptr,
                                                      const int* __restrict__ partial,
                                                      float* __restrict__ isq) {
    int v = blockIdx.x * 1024 + threadIdx.x;
    if (v < NN) {
        rowptr[v] += partial[blockIdx.x];
        isq[v] = rsqrtf((float)(deg[v] + 1));
    }
    if (v == 0) rowptr[NN] = partial[NBLK];
}

// csr stores BYTE offsets into a 64B-per-node group slab (src*64)
__global__ void csr_fill_k(const int* __restrict__ src, const int* __restrict__ dst,
                           const int* __restrict__ rowptr, int* __restrict__ cursor,
                           int* __restrict__ csrb) {
    int e = blockIdx.x * blockDim.x + threadIdx.x;
    if (e < NE) {
        int d = dst[e];
        int pos = atomicAdd(&cursor[d], 1);
        csrb[rowptr[d] + pos] = src[e] << 6;
    }
}

// ---------------- weight transpose+convert: WT[m][c][k] = bf16(W_m[k][c]) ----
__global__ void transpose_w_k(const float* __restrict__ W_in,
                              const float* __restrict__ W_layers,
                              ushort* __restrict__ WT) {
    int idx = blockIdx.x * blockDim.x + threadIdx.x;
    int m = idx >> 14;
    int c = (idx >> 7) & 127;
    int k = idx & 127;
    const float* W = (m == 0) ? W_in : (W_layers + (size_t)(m - 1) * HD * HD);
    WT[idx] = f2bf(W[k * HD + c]);
}

// ---------------- MFMA GEMM: out = A[nrows,128] @ W[128,128] -----------------
// MODE 0: A f32 (x).  h[r][c] = acc + bias[c];  hb(row-major) = bf16(h)
// MODE 1: A bf16 (hb). mhg[c>>5][r][c&31] = bf16(acc * isq[r])   (group-major)
template<int MODE>
__global__ __launch_bounds__(256) void gemm_mfma_k(const void* __restrict__ Av,
                                                   const ushort* __restrict__ WT,
                                                   const float* __restrict__ bs,
                                                   float* __restrict__ out_f32,
                                                   ushort* __restrict__ out_b16,
                                                   int nrows) {
    __shared__ ushort swT[HD * HD]; // 32 KB, XOR-swizzled [col][k]
    int tid = threadIdx.x;
    #pragma unroll
    for (int i = 0; i < 8; ++i) {
        int chunk = tid + i * 256;
        int lin = chunk << 4;
        int n = lin >> 8;
        int swz = lin ^ ((n & 7) << 4);
        *(float4*)((char*)swT + swz) = *(const float4*)(WT + chunk * 8);
    }
    __syncthreads();

    int w = tid >> 6, l = tid & 63;
    int ar = l & 15, ag = l >> 4;
    int r0 = blockIdx.x * 64 + w * 16;
    int arow = r0 + ar;
    bool arow_ok = arow < nrows;

    short8 afr[4];
    #pragma unroll
    for (int ks = 0; ks < 4; ++ks) {
        if (MODE == 0) {
            short8 fr = {0,0,0,0,0,0,0,0};
            if (arow_ok) {
                const float* Af = (const float*)Av;
                float4 p0 = *(const float4*)(Af + (size_t)arow * HD + ks * 32 + ag * 8);
                float4 p1 = *(const float4*)(Af + (size_t)arow * HD + ks * 32 + ag * 8 + 4);
                fr[0] = (short)f2bf(p0.x); fr[1] = (short)f2bf(p0.y);
                fr[2] = (short)f2bf(p0.z); fr[3] = (short)f2bf(p0.w);
                fr[4] = (short)f2bf(p1.x); fr[5] = (short)f2bf(p1.y);
                fr[6] = (short)f2bf(p1.z); fr[7] = (short)f2bf(p1.w);
            }
            afr[ks] = fr;
        } else {
            const ushort* Ab = (const ushort*)Av;
            afr[ks] = arow_ok ? *(const short8*)(Ab + (size_t)arow * HD + ks * 32 + ag * 8)
                              : short8{0,0,0,0,0,0,0,0};
        }
    }

    f32x4 acc[8];
    #pragma unroll
    for (int t = 0; t < 8; ++t) acc[t] = f32x4{0.f, 0.f, 0.f, 0.f};

    #pragma unroll
    for (int ks = 0; ks < 4; ++ks) {
        #pragma unroll
        for (int t = 0; t < 8; ++t) {
            int n = t * 16 + ar;
            int lin = (n << 8) + ks * 64 + ag * 16;
            int swz = lin ^ ((ar & 7) << 4);
            short8 b = *(const short8*)((const char*)swT + swz);
            acc[t] = __builtin_amdgcn_mfma_f32_16x16x32_bf16(afr[ks], b, acc[t], 0, 0, 0);
        }
    }

    #pragma unroll
    for (int q = 0; q < 4; ++q) {
        int row = r0 + ag * 4 + q;
        if (row >= nrows) continue;
        if (MODE == 0) {
            #pragma unroll
            for (int t = 0; t < 8; ++t) {
                int col = t * 16 + ar;
                float v = acc[t][q] + bs[col];
                out_f32[(size_t)row * HD + col] = v;
                out_b16[(size_t)row * HD + col] = f2bf(v);
            }
        } else {
            float s = bs[row];
            #pragma unroll
            for (int t = 0; t < 8; ++t) {
                int col = t * 16 + ar;
                size_t gi = ((size_t)(col >> 5) * NN + (size_t)row) * 32 + (col & 31);
                out_b16[gi] = f2bf(acc[t][q] * s);
            }
        }
    }
}

// ---------------- aggregation: 4 channel-group passes, L2-resident slab ------
// Per (node v, group g): sum 32 channels of mhg[g] over in-edges (+self),
// then h[v][g*32..] = gelu(isq*sum + b) + h;  hb likewise (bf16).
// Wave = 4 edge-slots x 16 lanes; one load serves 4 edges.
template<int WRITE_HB>
__global__ __launch_bounds__(256) void aggregate4_k(const ushort* __restrict__ mhg,
                                                    const int* __restrict__ rowptr,
                                                    const int* __restrict__ csrb,
                                                    const float* __restrict__ isq,
                                                    const float* __restrict__ bias,
                                                    float* __restrict__ h,
                                                    ushort* __restrict__ hb) {
    int bid = blockIdx.x;
    int g = bid / GBLK;                       // g-major: resident blocks share a slab
    int v = (bid - g * GBLK) * 4 + (threadIdx.x >> 6);
    int lane = threadIdx.x & 63;
    int sub = lane & 15, grp = lane >> 4;

    const char* slab = (const char*)mhg + (size_t)g * NN * 64 + sub * 4;
    int2 rp = *(const int2*)&rowptr[v];
    float accx = 0.f, accy = 0.f;

    for (int i = rp.x; i < rp.y; i += 64) {
        int cnt = min(64, rp.y - i);
        int offs = (i + lane < rp.y) ? __builtin_nontemporal_load(&csrb[i + lane]) : 0;
        int nf = cnt >> 2, r = cnt & 3;
        int bp = grp << 2;                    // ds_bpermute byte addr of lane (j*4+grp)
        for (int j = 0; j < nf; ++j) {
            int o = __builtin_amdgcn_ds_bpermute(bp, offs);
            bp += 16;
            uint p = *(const uint*)(slab + o);
            accx += u2f(p << 16); accy += u2f(p & 0xffff0000u);
        }
        if (r) {
            int o = __builtin_amdgcn_ds_bpermute(bp, offs);
            uint p = *(const uint*)(slab + o);
            bool ok = grp < r;
            accx += ok ? u2f(p << 16) : 0.f;
            accy += ok ? u2f(p & 0xffff0000u) : 0.f;
        }
    }
    // reduce across the 4 edge-slots
    accx += __shfl_xor(accx, 16); accy += __shfl_xor(accy, 16);
    accx += __shfl_xor(accx, 32); accy += __shfl_xor(accy, 32);

    if (grp == 0) {
        uint sp = *(const uint*)(slab + ((size_t)v << 6)); // self loop
        accx += u2f(sp << 16); accy += u2f(sp & 0xffff0000u);
        float is = isq[v];
        float2 b = *(const float2*)&bias[g * 32 + sub * 2];
        float ax = accx * is + b.x;
        float ay = accy * is + b.y;
        float gx = 0.5f * ax * (1.f + erff(ax * 0.70710678118654752f));
        float gy = 0.5f * ay * (1.f + erff(ay * 0.70710678118654752f));
        float* hp = h + (size_t)v * HD + g * 32 + sub * 2;
        float hx = __builtin_nontemporal_load(hp);
        float hy = __builtin_nontemporal_load(hp + 1);
        hx += gx; hy += gy;
        __builtin_nontemporal_store(hx, hp);
        __builtin_nontemporal_store(hy, hp + 1);
        if (WRITE_HB) {
            uint packed = ((uint)f2bf(hx)) | (((uint)f2bf(hy)) << 16);
            __builtin_nontemporal_store(packed,
                (uint*)((char*)hb + ((size_t)v << 8) + g * 64 + sub * 4));
        }
    }
}

// ---------------- launch ----------------

static inline size_t align_up(size_t x, size_t a) { return (x + a - 1) & ~(a - 1); }

extern "C" void kernel_launch(void* const* d_in, const int* in_sizes, int n_in,
                              void* d_out, int out_size, void* d_ws, size_t ws_size,
                              hipStream_t stream) {
    const float* x        = (const float*)d_in[0];
    const int*   eidx     = (const int*)d_in[1];
    const float* W_in     = (const float*)d_in[2];
    const float* b_in     = (const float*)d_in[3];
    const float* W_layers = (const float*)d_in[4];
    const float* b_layers = (const float*)d_in[5];
    float* h = (float*)d_out;

    const int* src = eidx;
    const int* dst = eidx + NE;

    // workspace carve-up (~33 MB)
    char* p = (char*)d_ws;
    ushort* mhg = (ushort*)p;     p += align_up(sizeof(ushort) * (size_t)NN * HD, 256);
    ushort* hb = (ushort*)p;      p += align_up(sizeof(ushort) * (size_t)NN * HD, 256);
    ushort* WT = (ushort*)p;      p += align_up(sizeof(ushort) * 4 * HD * HD, 256);
    float* isq = (float*)p;       p += align_up(sizeof(float) * NN, 256);
    int* deg = (int*)p;           // deg and cursor adjacent -> one memset
    int* cursor = deg + NN;       p += align_up(sizeof(int) * 2 * NN, 256);
    int* rowptr = (int*)p;        p += align_up(sizeof(int) * (NN + 1), 256);
    int* partial = (int*)p;       p += align_up(sizeof(int) * (NBLK + 1), 256);
    int* csrb = (int*)p;          p += align_up(sizeof(int) * NE, 256);

    hipMemsetAsync(deg, 0, sizeof(int) * 2 * NN, stream);

    transpose_w_k<<<(4 * HD * HD) / 256, 256, 0, stream>>>(W_in, W_layers, WT);
    count_deg_k<<<(NE + 255) / 256, 256, 0, stream>>>(dst, deg);
    scan_partial_k<<<NBLK, 1024, 0, stream>>>(deg, rowptr, partial);
    scan_partials2_k<<<1, 64, 0, stream>>>(partial);
    add_off_isq_k<<<NBLK, 1024, 0, stream>>>(deg, rowptr, partial, isq);
    csr_fill_k<<<(NE + 255) / 256, 256, 0, stream>>>(src, dst, rowptr, cursor, csrb);

    int gblocks = (NN + 63) / 64; // 782
    // h = x @ W_in + b_in ; hb = bf16(h)
    gemm_mfma_k<0><<<gblocks, 256, 0, stream>>>(x, WT, b_in, h, hb, NN);

    for (int l = 0; l < NL; ++l) {
        // mhg = bf16((hb @ W_l) * isq[row]), group-major
        gemm_mfma_k<1><<<gblocks, 256, 0, stream>>>(hb, WT + (size_t)(l + 1) * HD * HD,
                                                    isq, nullptr, mhg, NN);
        // h = gelu(isq*(sum mhg[src] + mhg[v]) + b_l) + h ; hb = bf16(h) except last
        if (l < NL - 1)
            aggregate4_k<1><<<4 * GBLK, 256, 0, stream>>>(mhg, rowptr, csrb, isq,
                                                          b_layers + (size_t)l * HD, h, hb);
        else
            aggregate4_k<0><<<4 * GBLK, 256, 0, stream>>>(mhg, rowptr, csrb, isq,
                                                          b_layers + (size_t)l * HD, h, hb);
    }
}

// Round 7
// 220.989 us; speedup vs baseline: 1.8522x; 1.8522x over previous
//
#include <hip/hip_runtime.h>
#include <hip/hip_bf16.h>
#include <math.h>

#define NN 50000
#define NE 600000
#define HD 128
#define NL 3
#define NBLK 49   // ceil(NN/1024)

typedef __attribute__((ext_vector_type(8))) short short8;
typedef __attribute__((ext_vector_type(4))) float f32x4;

__device__ __forceinline__ ushort f2bf(float v) {
    union { float f; unsigned u; } c; c.f = v;
    unsigned u = c.u;
    u = (u + 0x7fffu + ((u >> 16) & 1u)) >> 16;
    return (ushort)u;
}
__device__ __forceinline__ float u2f(uint u) {
    union { uint u; float f; } c; c.u = u; return c.f;
}

// ---------------- degree ----------------

__global__ void count_deg_k(const int* __restrict__ dst, int* __restrict__ deg) {
    int e = blockIdx.x * blockDim.x + threadIdx.x;
    if (e < NE) atomicAdd(&deg[dst[e]], 1);
}

// ---------------- 3-phase scan: deg -> rowptr (exclusive) ----------------

__global__ __launch_bounds__(1024) void scan_partial_k(const int* __restrict__ deg,
                                                       int* __restrict__ rowptr,
                                                       int* __restrict__ partial) {
    __shared__ int wsum[16];
    int tid = threadIdx.x;
    int lane = tid & 63, w = tid >> 6;
    int v = blockIdx.x * 1024 + tid;
    int x = (v < NN) ? deg[v] : 0;
    int s = x;
    #pragma unroll
    for (int off = 1; off < 64; off <<= 1) {
        int t = __shfl_up(s, off);
        if (lane >= off) s += t;
    }
    if (lane == 63) wsum[w] = s;
    __syncthreads();
    if (w == 0) {
        int t = (lane < 16) ? wsum[lane] : 0;
        #pragma unroll
        for (int off = 1; off < 16; off <<= 1) {
            int u = __shfl_up(t, off);
            if (lane >= off) t += u;
        }
        if (lane < 16) wsum[lane] = t;
    }
    __syncthreads();
    int incl = s + ((w > 0) ? wsum[w - 1] : 0);
    if (v < NN) rowptr[v] = incl - x;
    if (tid == 1023) partial[blockIdx.x] = incl;
}

__global__ void scan_partials2_k(int* __restrict__ partial) {
    int lane = threadIdx.x & 63;
    int x = (lane < NBLK) ? partial[lane] : 0;
    int s = x;
    #pragma unroll
    for (int off = 1; off < 64; off <<= 1) {
        int t = __shfl_up(s, off);
        if (lane >= off) s += t;
    }
    if (lane < NBLK) partial[lane] = s - x;
    if (lane == NBLK - 1) partial[NBLK] = s;
}

__global__ __launch_bounds__(1024) void add_off_isq_k(const int* __restrict__ deg,
                                                      int* __restrict__ rowptr,
                                                      const int* __restrict__ partial,
                                                      float* __restrict__ isq) {
    int v = blockIdx.x * 1024 + threadIdx.x;
    if (v < NN) {
        rowptr[v] += partial[blockIdx.x];
        isq[v] = rsqrtf((float)(deg[v] + 1));
    }
    if (v == 0) rowptr[NN] = partial[NBLK];
}

// csr stores BYTE offsets (src*256)
__global__ void csr_fill_k(const int* __restrict__ src, const int* __restrict__ dst,
                           const int* __restrict__ rowptr, int* __restrict__ cursor,
                           int* __restrict__ csrb) {
    int e = blockIdx.x * blockDim.x + threadIdx.x;
    if (e < NE) {
        int d = dst[e];
        int pos = atomicAdd(&cursor[d], 1);
        csrb[rowptr[d] + pos] = src[e] << 8;
    }
}

// ---------------- weight transpose+convert: WT[m][c][k] = bf16(W_m[k][c]) ----
__global__ void transpose_w_k(const float* __restrict__ W_in,
                              const float* __restrict__ W_layers,
                              ushort* __restrict__ WT) {
    int idx = blockIdx.x * blockDim.x + threadIdx.x;
    int m = idx >> 14;
    int c = (idx >> 7) & 127;
    int k = idx & 127;
    const float* W = (m == 0) ? W_in : (W_layers + (size_t)(m - 1) * HD * HD);
    WT[idx] = f2bf(W[k * HD + c]);
}

// ---------------- MFMA GEMM: out = A[nrows,128] @ W[128,128] -----------------
// MODE 0: A f32 (x).  h[r][c] = acc + bias[c];  hb = bf16(h)
// MODE 1: A bf16 (hb). mh[r][c] = bf16(acc * isq[r])
template<int MODE>
__global__ __launch_bounds__(256) void gemm_mfma_k(const void* __restrict__ Av,
                                                   const ushort* __restrict__ WT,
                                                   const float* __restrict__ bs,
                                                   float* __restrict__ out_f32,
                                                   ushort* __restrict__ out_b16,
                                                   int nrows) {
    __shared__ ushort swT[HD * HD]; // 32 KB, XOR-swizzled [col][k]
    int tid = threadIdx.x;
    #pragma unroll
    for (int i = 0; i < 8; ++i) {
        int chunk = tid + i * 256;
        int lin = chunk << 4;
        int n = lin >> 8;
        int swz = lin ^ ((n & 7) << 4);
        *(float4*)((char*)swT + swz) = *(const float4*)(WT + chunk * 8);
    }
    __syncthreads();

    int w = tid >> 6, l = tid & 63;
    int ar = l & 15, ag = l >> 4;
    int r0 = blockIdx.x * 64 + w * 16;
    int arow = r0 + ar;
    bool arow_ok = arow < nrows;

    short8 afr[4];
    #pragma unroll
    for (int ks = 0; ks < 4; ++ks) {
        if (MODE == 0) {
            short8 fr = {0,0,0,0,0,0,0,0};
            if (arow_ok) {
                const float* Af = (const float*)Av;
                float4 p0 = *(const float4*)(Af + (size_t)arow * HD + ks * 32 + ag * 8);
                float4 p1 = *(const float4*)(Af + (size_t)arow * HD + ks * 32 + ag * 8 + 4);
                fr[0] = (short)f2bf(p0.x); fr[1] = (short)f2bf(p0.y);
                fr[2] = (short)f2bf(p0.z); fr[3] = (short)f2bf(p0.w);
                fr[4] = (short)f2bf(p1.x); fr[5] = (short)f2bf(p1.y);
                fr[6] = (short)f2bf(p1.z); fr[7] = (short)f2bf(p1.w);
            }
            afr[ks] = fr;
        } else {
            const ushort* Ab = (const ushort*)Av;
            afr[ks] = arow_ok ? *(const short8*)(Ab + (size_t)arow * HD + ks * 32 + ag * 8)
                              : short8{0,0,0,0,0,0,0,0};
        }
    }

    f32x4 acc[8];
    #pragma unroll
    for (int t = 0; t < 8; ++t) acc[t] = f32x4{0.f, 0.f, 0.f, 0.f};

    #pragma unroll
    for (int ks = 0; ks < 4; ++ks) {
        #pragma unroll
        for (int t = 0; t < 8; ++t) {
            int n = t * 16 + ar;
            int lin = (n << 8) + ks * 64 + ag * 16;
            int swz = lin ^ ((ar & 7) << 4);
            short8 b = *(const short8*)((const char*)swT + swz);
            acc[t] = __builtin_amdgcn_mfma_f32_16x16x32_bf16(afr[ks], b, acc[t], 0, 0, 0);
        }
    }

    #pragma unroll
    for (int q = 0; q < 4; ++q) {
        int row = r0 + ag * 4 + q;
        if (row >= nrows) continue;
        if (MODE == 0) {
            #pragma unroll
            for (int t = 0; t < 8; ++t) {
                int col = t * 16 + ar;
                float v = acc[t][q] + bs[col];
                out_f32[(size_t)row * HD + col] = v;
                out_b16[(size_t)row * HD + col] = f2bf(v);
            }
        } else {
            float s = bs[row];
            #pragma unroll
            for (int t = 0; t < 8; ++t) {
                int col = t * 16 + ar;
                out_b16[(size_t)row * HD + col] = f2bf(acc[t][q] * s);
            }
        }
    }
}

// ---------------- aggregation: one wave per node, MLP-8 clean unroll ---------
// h[v] = gelu( isq[v]*(sum_in mh[src] + mh[v]) + b ) + h[v];  hb = bf16(h)
template<int WRITE_HB>
__global__ __launch_bounds__(256) void aggregate_k(const ushort* __restrict__ mh,
                                                   const int* __restrict__ rowptr,
                                                   const int* __restrict__ csrb,
                                                   const float* __restrict__ isq,
                                                   const float* __restrict__ bias,
                                                   float* __restrict__ h,
                                                   ushort* __restrict__ hb) {
    int gw = (int)((blockIdx.x * blockDim.x + threadIdx.x) >> 6);
    int lane = threadIdx.x & 63;
    if (gw >= NN) return;
    int v = gw;
    int2 rp = *(const int2*)&rowptr[v];
    const char* mh_lane = (const char*)mh + lane * 4; // this lane's 2 channels

    // self-loop init
    uint sp = *(const uint*)(mh_lane + ((size_t)v << 8));
    float accx = u2f(sp << 16), accy = u2f(sp & 0xffff0000u);

    for (int i = rp.x; i < rp.y; i += 64) {
        int cnt = min(64, rp.y - i);
        int offs = (i + lane < rp.y) ? csrb[i + lane] : 0;
        int j = 0;
        // 8-wide branch-free body: 8 independent gathers in flight
        for (; j + 8 <= cnt; j += 8) {
            int o0 = __shfl(offs, j);
            int o1 = __shfl(offs, j + 1);
            int o2 = __shfl(offs, j + 2);
            int o3 = __shfl(offs, j + 3);
            int o4 = __shfl(offs, j + 4);
            int o5 = __shfl(offs, j + 5);
            int o6 = __shfl(offs, j + 6);
            int o7 = __shfl(offs, j + 7);
            uint p0 = *(const uint*)(mh_lane + o0);
            uint p1 = *(const uint*)(mh_lane + o1);
            uint p2 = *(const uint*)(mh_lane + o2);
            uint p3 = *(const uint*)(mh_lane + o3);
            uint p4 = *(const uint*)(mh_lane + o4);
            uint p5 = *(const uint*)(mh_lane + o5);
            uint p6 = *(const uint*)(mh_lane + o6);
            uint p7 = *(const uint*)(mh_lane + o7);
            accx += u2f(p0 << 16); accy += u2f(p0 & 0xffff0000u);
            accx += u2f(p1 << 16); accy += u2f(p1 & 0xffff0000u);
            accx += u2f(p2 << 16); accy += u2f(p2 & 0xffff0000u);
            accx += u2f(p3 << 16); accy += u2f(p3 & 0xffff0000u);
            accx += u2f(p4 << 16); accy += u2f(p4 & 0xffff0000u);
            accx += u2f(p5 << 16); accy += u2f(p5 & 0xffff0000u);
            accx += u2f(p6 << 16); accy += u2f(p6 & 0xffff0000u);
            accx += u2f(p7 << 16); accy += u2f(p7 & 0xffff0000u);
        }
        // 4-wide body
        for (; j + 4 <= cnt; j += 4) {
            int o0 = __shfl(offs, j);
            int o1 = __shfl(offs, j + 1);
            int o2 = __shfl(offs, j + 2);
            int o3 = __shfl(offs, j + 3);
            uint p0 = *(const uint*)(mh_lane + o0);
            uint p1 = *(const uint*)(mh_lane + o1);
            uint p2 = *(const uint*)(mh_lane + o2);
            uint p3 = *(const uint*)(mh_lane + o3);
            accx += u2f(p0 << 16); accy += u2f(p0 & 0xffff0000u);
            accx += u2f(p1 << 16); accy += u2f(p1 & 0xffff0000u);
            accx += u2f(p2 << 16); accy += u2f(p2 & 0xffff0000u);
            accx += u2f(p3 << 16); accy += u2f(p3 & 0xffff0000u);
        }
        for (; j < cnt; ++j) {
            int o = __shfl(offs, j);
            uint p = *(const uint*)(mh_lane + o);
            accx += u2f(p << 16); accy += u2f(p & 0xffff0000u);
        }
    }

    float is = isq[v];
    float2 b = *(const float2*)&bias[lane * 2];
    float ax = accx * is + b.x;
    float ay = accy * is + b.y;
    float gx = 0.5f * ax * (1.f + erff(ax * 0.70710678118654752f));
    float gy = 0.5f * ay * (1.f + erff(ay * 0.70710678118654752f));
    float* hp = h + (size_t)v * HD + lane * 2;
    float2 hv = *(const float2*)hp;
    hv.x += gx; hv.y += gy;
    *(float2*)hp = hv;
    if (WRITE_HB) {
        uint packed = ((uint)f2bf(hv.x)) | (((uint)f2bf(hv.y)) << 16);
        *(uint*)((char*)hb + ((size_t)v << 8) + lane * 4) = packed;
    }
}

// ---------------- launch ----------------

static inline size_t align_up(size_t x, size_t a) { return (x + a - 1) & ~(a - 1); }

extern "C" void kernel_launch(void* const* d_in, const int* in_sizes, int n_in,
                              void* d_out, int out_size, void* d_ws, size_t ws_size,
                              hipStream_t stream) {
    const float* x        = (const float*)d_in[0];
    const int*   eidx     = (const int*)d_in[1];
    const float* W_in     = (const float*)d_in[2];
    const float* b_in     = (const float*)d_in[3];
    const float* W_layers = (const float*)d_in[4];
    const float* b_layers = (const float*)d_in[5];
    float* h = (float*)d_out;

    const int* src = eidx;
    const int* dst = eidx + NE;

    // workspace carve-up (~33 MB)
    char* p = (char*)d_ws;
    ushort* mh = (ushort*)p;      p += align_up(sizeof(ushort) * (size_t)NN * HD, 256);
    ushort* hb = (ushort*)p;      p += align_up(sizeof(ushort) * (size_t)NN * HD, 256);
    ushort* WT = (ushort*)p;      p += align_up(sizeof(ushort) * 4 * HD * HD, 256);
    float* isq = (float*)p;       p += align_up(sizeof(float) * NN, 256);
    int* deg = (int*)p;           // deg and cursor adjacent -> one memset
    int* cursor = deg + NN;       p += align_up(sizeof(int) * 2 * NN, 256);
    int* rowptr = (int*)p;        p += align_up(sizeof(int) * (NN + 1), 256);
    int* partial = (int*)p;       p += align_up(sizeof(int) * (NBLK + 1), 256);
    int* csrb = (int*)p;          p += align_up(sizeof(int) * NE, 256);

    hipMemsetAsync(deg, 0, sizeof(int) * 2 * NN, stream);

    transpose_w_k<<<(4 * HD * HD) / 256, 256, 0, stream>>>(W_in, W_layers, WT);
    count_deg_k<<<(NE + 255) / 256, 256, 0, stream>>>(dst, deg);
    scan_partial_k<<<NBLK, 1024, 0, stream>>>(deg, rowptr, partial);
    scan_partials2_k<<<1, 64, 0, stream>>>(partial);
    add_off_isq_k<<<NBLK, 1024, 0, stream>>>(deg, rowptr, partial, isq);
    csr_fill_k<<<(NE + 255) / 256, 256, 0, stream>>>(src, dst, rowptr, cursor, csrb);

    int gblocks = (NN + 63) / 64; // 782
    // h = x @ W_in + b_in ; hb = bf16(h)
    gemm_mfma_k<0><<<gblocks, 256, 0, stream>>>(x, WT, b_in, h, hb, NN);

    for (int l = 0; l < NL; ++l) {
        // mh = bf16((hb @ W_l) * isq[row])
        gemm_mfma_k<1><<<gblocks, 256, 0, stream>>>(hb, WT + (size_t)(l + 1) * HD * HD,
                                                    isq, nullptr, mh, NN);
        // h = gelu(isq*(sum mh[src] + mh[v]) + b_l) + h ; hb = bf16(h) except last
        if (l < NL - 1)
            aggregate_k<1><<<(NN + 3) / 4, 256, 0, stream>>>(mh, rowptr, csrb, isq,
                                                             b_layers + (size_t)l * HD, h, hb);
        else
            aggregate_k<0><<<(NN + 3) / 4, 256, 0, stream>>>(mh, rowptr, csrb, isq,
                                                             b_layers + (size_t)l * HD, h, hb);
    }
}